// Round 1
// baseline (686.633 us; speedup 1.0000x reference)
//
#include <hip/hip_runtime.h>
#include <math.h>

#define BATCH 8
#define TOK   4096
#define HID   2048
#define BOT   64
#define CM    128
#define NBINS 16
#define TCH   32
#define LN_EPS 1e-5f

// ---------------------------------------------------------------------------
// Kernel 1: partial pooling over tokens.
// grid = (hchunk=2, tchunk=32, batch=8), block = 256 threads.
// Each thread owns one float4 (4 hidden cols), sums TOK/TCH = 128 tokens.
// Writes deterministic partials to ws: partial[b][tc][h] (8*32*2048 fp32 = 2MB)
// ---------------------------------------------------------------------------
__global__ void pool_partial(const float* __restrict__ hs,
                             float* __restrict__ partial) {
    const int tid = threadIdx.x;
    const int hc  = blockIdx.x;   // 0..1
    const int tc  = blockIdx.y;   // 0..31
    const int b   = blockIdx.z;   // 0..7
    const int h4  = hc * 256 + tid;           // float4 col index: 0..511

    const float4* hs4 = (const float4*)hs;    // [B][TOK][512]
    const int t0 = tc * (TOK / TCH);
    size_t base = ((size_t)b * TOK + t0) * (HID / 4) + h4;

    float4 acc = make_float4(0.f, 0.f, 0.f, 0.f);
    #pragma unroll 4
    for (int i = 0; i < TOK / TCH; ++i) {
        float4 v = hs4[base + (size_t)i * (HID / 4)];
        acc.x += v.x; acc.y += v.y; acc.z += v.z; acc.w += v.w;
    }
    float4* p4 = (float4*)partial;
    p4[((size_t)b * TCH + tc) * (HID / 4) + h4] = acc;
}

// ---------------------------------------------------------------------------
// Kernel 2: the whole MLP chain. 8 blocks (one per batch row), 256 threads.
// Total math ~400 KFLOP -- latency-bound, keep it simple and correct.
// ---------------------------------------------------------------------------
__device__ __forceinline__ float gelu_exact(float x) {
    // jax.nn.gelu(approximate=False): 0.5*x*(1+erf(x/sqrt(2)))
    return 0.5f * x * (1.0f + erff(x * 0.70710678118654752f));
}

__global__ void mlp_kernel(const float* __restrict__ partial,
                           const float* __restrict__ ew1, const float* __restrict__ eb1,
                           const float* __restrict__ eg,  const float* __restrict__ ebeta,
                           const float* __restrict__ ew2, const float* __restrict__ eb2,
                           const float* __restrict__ dw1, const float* __restrict__ db1,
                           const float* __restrict__ dg,  const float* __restrict__ dbeta,
                           const float* __restrict__ dw2, const float* __restrict__ db2,
                           const float* __restrict__ edges,
                           float* __restrict__ expanded) {
    __shared__ float pooled[HID];
    __shared__ float buf1[BOT];
    __shared__ float act1[BOT];
    __shared__ float commv[CM];
    __shared__ float act2[BOT];

    const int b   = blockIdx.x;
    const int tid = threadIdx.x;

    // ---- reduce partials -> pooled mean ----
    for (int i = 0; i < HID / 256; ++i) {
        int h = tid + i * 256;
        float s = 0.f;
        for (int tc = 0; tc < TCH; ++tc)
            s += partial[((size_t)b * TCH + tc) * HID + h];
        pooled[h] = s * (1.0f / TOK);
    }
    __syncthreads();

    // ---- enc layer 1: pooled[2048] @ ew1[2048x64] + eb1 ----
    if (tid < BOT) {
        float acc = eb1[tid];
        for (int h = 0; h < HID; ++h)
            acc += pooled[h] * ew1[h * BOT + tid];   // coalesced across 64 lanes
        buf1[tid] = acc;
    }
    __syncthreads();

    // ---- layernorm(64) + exact gelu ----
    if (tid < BOT) {
        float mu = 0.f;
        for (int j = 0; j < BOT; ++j) mu += buf1[j];
        mu *= (1.0f / BOT);
        float var = 0.f;
        for (int j = 0; j < BOT; ++j) { float d = buf1[j] - mu; var += d * d; }
        var *= (1.0f / BOT);
        float x = (buf1[tid] - mu) * rsqrtf(var + LN_EPS) * eg[tid] + ebeta[tid];
        act1[tid] = gelu_exact(x);
    }
    __syncthreads();

    // ---- enc layer 2: act1[64] @ ew2[64x128] + eb2, then quantize ----
    if (tid < CM) {
        float acc = eb2[tid];
        for (int j = 0; j < BOT; ++j)
            acc += act1[j] * ew2[j * CM + tid];
        // searchsorted(edges, x, 'left') = #(edges < x); b = clip(cnt-1, 0, 15)
        int cnt = 0;
        for (int i = 0; i <= NBINS; ++i) cnt += (edges[i] < acc) ? 1 : 0;
        int bi = cnt - 1;
        bi = bi < 0 ? 0 : (bi > NBINS - 1 ? NBINS - 1 : bi);
        float xq = 0.5f * (edges[bi] + edges[bi + 1]);
        float e0 = edges[0], eN = edges[NBINS];
        if (acc <= e0) xq = e0;
        if (acc >  eN) xq = eN;
        commv[tid] = xq;
    }
    __syncthreads();

    // ---- dec layer 1: commv[128] @ dw1[128x64] + db1 ----
    if (tid < BOT) {
        float acc = db1[tid];
        for (int c = 0; c < CM; ++c)
            acc += commv[c] * dw1[c * BOT + tid];
        buf1[tid] = acc;
    }
    __syncthreads();

    // ---- layernorm(64) + exact gelu ----
    if (tid < BOT) {
        float mu = 0.f;
        for (int j = 0; j < BOT; ++j) mu += buf1[j];
        mu *= (1.0f / BOT);
        float var = 0.f;
        for (int j = 0; j < BOT; ++j) { float d = buf1[j] - mu; var += d * d; }
        var *= (1.0f / BOT);
        float x = (buf1[tid] - mu) * rsqrtf(var + LN_EPS) * dg[tid] + dbeta[tid];
        act2[tid] = gelu_exact(x);
    }
    __syncthreads();

    // ---- dec layer 2: act2[64] @ dw2[64x2048] + db2; pre-scale by 0.1 ----
    for (int i = 0; i < HID / 256; ++i) {
        int h = tid + i * 256;
        float acc = db2[h];
        for (int j = 0; j < BOT; ++j)
            acc += act2[j] * dw2[j * HID + h];       // coalesced across lanes
        expanded[(size_t)b * HID + h] = 0.1f * acc;
    }
}

// ---------------------------------------------------------------------------
// Kernel 3: out = hs + expanded_scaled (broadcast over tokens). float4 grid-stride.
// ---------------------------------------------------------------------------
__global__ void add_kernel(const float* __restrict__ hs,
                           const float* __restrict__ expanded,
                           float* __restrict__ out) {
    const float4* hs4 = (const float4*)hs;
    const float4* ex4 = (const float4*)expanded;
    float4* out4 = (float4*)out;

    const size_t total4   = (size_t)BATCH * TOK * (HID / 4);
    const size_t perBatch = (size_t)TOK * (HID / 4);
    const size_t stride   = (size_t)gridDim.x * blockDim.x;

    for (size_t i = (size_t)blockIdx.x * blockDim.x + threadIdx.x;
         i < total4; i += stride) {
        size_t b  = i / perBatch;
        size_t h4 = i % (HID / 4);
        float4 v = hs4[i];
        float4 e = ex4[b * (HID / 4) + h4];   // 64 KB, L1/L2-resident
        v.x += e.x; v.y += e.y; v.z += e.z; v.w += e.w;
        out4[i] = v;
    }
}

extern "C" void kernel_launch(void* const* d_in, const int* in_sizes, int n_in,
                              void* d_out, int out_size, void* d_ws, size_t ws_size,
                              hipStream_t stream) {
    const float* hs    = (const float*)d_in[0];
    const float* ew1   = (const float*)d_in[1];
    const float* eb1   = (const float*)d_in[2];
    const float* eg    = (const float*)d_in[3];
    const float* ebeta = (const float*)d_in[4];
    const float* ew2   = (const float*)d_in[5];
    const float* eb2   = (const float*)d_in[6];
    const float* dw1   = (const float*)d_in[7];
    const float* db1   = (const float*)d_in[8];
    const float* dg    = (const float*)d_in[9];
    const float* dbeta = (const float*)d_in[10];
    const float* dw2   = (const float*)d_in[11];
    const float* db2   = (const float*)d_in[12];
    const float* edges = (const float*)d_in[13];
    float* out = (float*)d_out;

    float* partial  = (float*)d_ws;                         // 8*32*2048 fp32 = 2 MB
    float* expanded = partial + (size_t)BATCH * TCH * HID;  // 8*2048 fp32 = 64 KB

    pool_partial<<<dim3(2, TCH, BATCH), 256, 0, stream>>>(hs, partial);
    mlp_kernel<<<BATCH, 256, 0, stream>>>(partial,
                                          ew1, eb1, eg, ebeta, ew2, eb2,
                                          dw1, db1, dg, dbeta, dw2, db2,
                                          edges, expanded);
    add_kernel<<<8192, 256, 0, stream>>>(hs, expanded, out);
}

// Round 2
// 547.931 us; speedup vs baseline: 1.2531x; 1.2531x over previous
//
#include <hip/hip_runtime.h>
#include <math.h>

#define BATCH 8
#define TOK   4096
#define HID   2048
#define BOT   64
#define CM    128
#define NBINS 16
#define TCH   32
#define LN_EPS 1e-5f

// ---------------------------------------------------------------------------
// Kernel 1: partial pooling over tokens.
// grid = (hchunk=2, tchunk=32, batch=8), block = 256 threads.
// Each thread owns one float4 (4 hidden cols), sums TOK/TCH = 128 tokens.
// ---------------------------------------------------------------------------
__global__ void pool_partial(const float* __restrict__ hs,
                             float* __restrict__ partial) {
    const int tid = threadIdx.x;
    const int hc  = blockIdx.x;   // 0..1
    const int tc  = blockIdx.y;   // 0..31
    const int b   = blockIdx.z;   // 0..7
    const int h4  = hc * 256 + tid;           // float4 col index: 0..511

    const float4* hs4 = (const float4*)hs;    // [B][TOK][512]
    const int t0 = tc * (TOK / TCH);
    size_t base = ((size_t)b * TOK + t0) * (HID / 4) + h4;

    float4 acc = make_float4(0.f, 0.f, 0.f, 0.f);
    #pragma unroll 4
    for (int i = 0; i < TOK / TCH; ++i) {
        float4 v = hs4[base + (size_t)i * (HID / 4)];
        acc.x += v.x; acc.y += v.y; acc.z += v.z; acc.w += v.w;
    }
    float4* p4 = (float4*)partial;
    p4[((size_t)b * TCH + tc) * (HID / 4) + h4] = acc;
}

// ---------------------------------------------------------------------------
// Kernel 2: MLP chain, 8 blocks x 1024 threads.
// enc1 (2048x64) parallelized as 16 h-chunks x 64 outs + LDS reduce.
// ---------------------------------------------------------------------------
__device__ __forceinline__ float gelu_exact(float x) {
    return 0.5f * x * (1.0f + erff(x * 0.70710678118654752f));
}

__global__ void __launch_bounds__(1024)
mlp_kernel(const float* __restrict__ partial,
           const float* __restrict__ ew1, const float* __restrict__ eb1,
           const float* __restrict__ eg,  const float* __restrict__ ebeta,
           const float* __restrict__ ew2, const float* __restrict__ eb2,
           const float* __restrict__ dw1, const float* __restrict__ db1,
           const float* __restrict__ dg,  const float* __restrict__ dbeta,
           const float* __restrict__ dw2, const float* __restrict__ db2,
           const float* __restrict__ edges,
           float* __restrict__ expanded) {
    __shared__ float pooled[HID];          // 8 KB
    __shared__ float red[16 * BOT];        // 4 KB
    __shared__ float buf1[BOT];
    __shared__ float act1[BOT];
    __shared__ float commv[CM];
    __shared__ float act2[BOT];

    const int b   = blockIdx.x;
    const int tid = threadIdx.x;

    // ---- reduce partials -> pooled mean (float4, 512 active threads) ----
    if (tid < HID / 4) {
        const float4* p4 = (const float4*)partial;
        float4 s = make_float4(0.f, 0.f, 0.f, 0.f);
        #pragma unroll 8
        for (int tc = 0; tc < TCH; ++tc) {
            float4 v = p4[((size_t)b * TCH + tc) * (HID / 4) + tid];
            s.x += v.x; s.y += v.y; s.z += v.z; s.w += v.w;
        }
        const float inv = 1.0f / TOK;
        ((float4*)pooled)[tid] = make_float4(s.x * inv, s.y * inv, s.z * inv, s.w * inv);
    }
    __syncthreads();

    // ---- enc layer 1: pooled[2048] @ ew1[2048x64] + eb1 ----
    {
        const int o = tid & 63;        // output col
        const int c = tid >> 6;        // h-chunk 0..15 (128 h each)
        const int h0 = c * (HID / 16);
        float acc = 0.f;
        #pragma unroll 8
        for (int i = 0; i < HID / 16; ++i) {
            int h = h0 + i;
            acc += pooled[h] * ew1[h * BOT + o];   // coalesced; pooled = LDS broadcast
        }
        red[tid] = acc;
    }
    __syncthreads();
    if (tid < BOT) {
        float acc = eb1[tid];
        #pragma unroll
        for (int c = 0; c < 16; ++c) acc += red[c * BOT + tid];
        buf1[tid] = acc;
    }
    __syncthreads();

    // ---- layernorm(64) + exact gelu ----
    if (tid < BOT) {
        float mu = 0.f;
        for (int j = 0; j < BOT; ++j) mu += buf1[j];
        mu *= (1.0f / BOT);
        float var = 0.f;
        for (int j = 0; j < BOT; ++j) { float d = buf1[j] - mu; var += d * d; }
        var *= (1.0f / BOT);
        float x = (buf1[tid] - mu) * rsqrtf(var + LN_EPS) * eg[tid] + ebeta[tid];
        act1[tid] = gelu_exact(x);
    }
    __syncthreads();

    // ---- enc layer 2: act1[64] @ ew2[64x128] + eb2, then quantize ----
    if (tid < CM) {
        float acc = eb2[tid];
        #pragma unroll 8
        for (int j = 0; j < BOT; ++j)
            acc += act1[j] * ew2[j * CM + tid];
        int cnt = 0;
        #pragma unroll
        for (int i = 0; i <= NBINS; ++i) cnt += (edges[i] < acc) ? 1 : 0;
        int bi = cnt - 1;
        bi = bi < 0 ? 0 : (bi > NBINS - 1 ? NBINS - 1 : bi);
        float xq = 0.5f * (edges[bi] + edges[bi + 1]);
        float e0 = edges[0], eN = edges[NBINS];
        if (acc <= e0) xq = e0;
        if (acc >  eN) xq = eN;
        commv[tid] = xq;
    }
    __syncthreads();

    // ---- dec layer 1: commv[128] @ dw1[128x64] + db1 ----
    if (tid < BOT) {
        float acc = db1[tid];
        #pragma unroll 8
        for (int c = 0; c < CM; ++c)
            acc += commv[c] * dw1[c * BOT + tid];
        buf1[tid] = acc;
    }
    __syncthreads();

    // ---- layernorm(64) + exact gelu ----
    if (tid < BOT) {
        float mu = 0.f;
        for (int j = 0; j < BOT; ++j) mu += buf1[j];
        mu *= (1.0f / BOT);
        float var = 0.f;
        for (int j = 0; j < BOT; ++j) { float d = buf1[j] - mu; var += d * d; }
        var *= (1.0f / BOT);
        float x = (buf1[tid] - mu) * rsqrtf(var + LN_EPS) * dg[tid] + dbeta[tid];
        act2[tid] = gelu_exact(x);
    }
    __syncthreads();

    // ---- dec layer 2: act2[64] @ dw2[64x2048] + db2; pre-scale by 0.1 ----
    #pragma unroll
    for (int i = 0; i < HID / 1024; ++i) {
        int h = tid + i * 1024;
        float acc = db2[h];
        #pragma unroll 8
        for (int j = 0; j < BOT; ++j)
            acc += act2[j] * dw2[j * HID + h];       // coalesced across lanes
        expanded[(size_t)b * HID + h] = 0.1f * acc;
    }
}

// ---------------------------------------------------------------------------
// Kernel 3: out = hs + expanded_scaled. 3D grid, no integer division.
// grid = (hchunk=2, tokchunk=1024, batch=8), block=256; 4 tokens per thread.
// ---------------------------------------------------------------------------
__global__ void add_kernel(const float* __restrict__ hs,
                           const float* __restrict__ expanded,
                           float* __restrict__ out) {
    const int tid = threadIdx.x;
    const int hc  = blockIdx.x;   // 0..1
    const int tc  = blockIdx.y;   // 0..1023 (4 tokens each)
    const int b   = blockIdx.z;   // 0..7
    const int h4  = hc * 256 + tid;

    const float4* hs4 = (const float4*)hs;
    const float4* ex4 = (const float4*)expanded;
    float4* out4 = (float4*)out;

    float4 e = ex4[(size_t)b * (HID / 4) + h4];   // L2-resident broadcast vector
    size_t base = ((size_t)b * TOK + (size_t)tc * 4) * (HID / 4) + h4;

    #pragma unroll
    for (int t = 0; t < 4; ++t) {
        size_t idx = base + (size_t)t * (HID / 4);
        float4 v = hs4[idx];
        v.x += e.x; v.y += e.y; v.z += e.z; v.w += e.w;
        out4[idx] = v;
    }
}

extern "C" void kernel_launch(void* const* d_in, const int* in_sizes, int n_in,
                              void* d_out, int out_size, void* d_ws, size_t ws_size,
                              hipStream_t stream) {
    const float* hs    = (const float*)d_in[0];
    const float* ew1   = (const float*)d_in[1];
    const float* eb1   = (const float*)d_in[2];
    const float* eg    = (const float*)d_in[3];
    const float* ebeta = (const float*)d_in[4];
    const float* ew2   = (const float*)d_in[5];
    const float* eb2   = (const float*)d_in[6];
    const float* dw1   = (const float*)d_in[7];
    const float* db1   = (const float*)d_in[8];
    const float* dg    = (const float*)d_in[9];
    const float* dbeta = (const float*)d_in[10];
    const float* dw2   = (const float*)d_in[11];
    const float* db2   = (const float*)d_in[12];
    const float* edges = (const float*)d_in[13];
    float* out = (float*)d_out;

    float* partial  = (float*)d_ws;                         // 2 MB
    float* expanded = partial + (size_t)BATCH * TCH * HID;  // 64 KB

    pool_partial<<<dim3(2, TCH, BATCH), 256, 0, stream>>>(hs, partial);
    mlp_kernel<<<BATCH, 1024, 0, stream>>>(partial,
                                           ew1, eb1, eg, ebeta, ew2, eb2,
                                           dw1, db1, dg, dbeta, dw2, db2,
                                           edges, expanded);
    add_kernel<<<dim3(2, TOK / 4, BATCH), 256, 0, stream>>>(hs, expanded, out);
}